// Round 1
// baseline (189.860 us; speedup 1.0000x reference)
//
#include <hip/hip_runtime.h>
#include <math.h>

#define TLEN 16384
#define MROW 8
#define NPAIR 30      // pairs (m,k) with m<=k<=min(m+4,7) — only lags 0..4 are consumed
#define NT 1024
#define EPSV 1e-8f

// Single fused kernel: one block per batch (grid=256, 1024 threads).
// Each block streams its 8x16384 rows once (float4, coalesced), accumulates the
// 30 lag-products in registers, block-reduces, and runs the epilogue in-block.
// No workspace, no second launch: removes the 512 MiB ws re-poison fills
// (~2x77 us) that dominated the 187.8 us timed region.
__global__ __launch_bounds__(NT, 4)
void ssf_fused(const float* __restrict__ X, float* __restrict__ out) {
    const int n   = blockIdx.x;
    const int tid = threadIdx.x;
    const int TV  = TLEN / 4;        // 4096 float4 per row
    const float4* Xv = reinterpret_cast<const float4*>(X + (size_t)n * MROW * TLEN);

    float acc[NPAIR];
#pragma unroll
    for (int p = 0; p < NPAIR; ++p) acc[p] = 0.f;

    // TV/NT = 4 iterations, fully unrolled; 8 independent float4 loads per iter
#pragma unroll
    for (int i = 0; i < TV / NT; ++i) {
        const int it = i * NT + tid;
        float4 x[MROW];
#pragma unroll
        for (int m = 0; m < MROW; ++m) x[m] = Xv[m * TV + it];
        const float* xv = reinterpret_cast<const float*>(x);
#pragma unroll
        for (int e = 0; e < 4; ++e) {
            int p = 0;
#pragma unroll
            for (int m = 0; m < MROW; ++m) {
                const float vm = xv[m * 4 + e];
                const int kmax = (m + 4 < MROW - 1) ? m + 4 : MROW - 1;
#pragma unroll
                for (int k = m; k <= kmax; ++k) {
                    acc[p++] += vm * xv[k * 4 + e];
                }
            }
        }
    }

    // 64-lane butterfly reduction per accumulator
#pragma unroll
    for (int p = 0; p < NPAIR; ++p) {
        float v = acc[p];
#pragma unroll
        for (int off = 32; off > 0; off >>= 1) v += __shfl_down(v, off, 64);
        acc[p] = v;
    }

    __shared__ float partial[NT / 64][NPAIR];   // 16 waves x 30
    const int wave = tid >> 6;
    const int lane = tid & 63;
    if (lane == 0) {
#pragma unroll
        for (int p = 0; p < NPAIR; ++p) partial[wave][p] = acc[p];
    }
    __syncthreads();

    __shared__ float Cm[MROW][MROW];
    if (tid < NPAIR) {
        float s = 0.f;
#pragma unroll
        for (int w = 0; w < NT / 64; ++w) s += partial[w][tid];
        s *= (1.0f / (float)TLEN);
        // decode linear pair index -> (m,k): m<=k<=min(m+4,7)
        int p = tid, m = 0;
        for (;;) {
            const int cnt = ((m + 4 < MROW - 1) ? m + 4 : MROW - 1) - m + 1;
            if (p < cnt) break;
            p -= cnt; ++m;
        }
        const int k = m + p;
        Cm[m][k] = s;
        Cm[k][m] = s;
    }
    __syncthreads();

    if (tid == 0) {
        const int rows[15] = {0,0,0,0,0, 1,1,1,1, 2,2,2, 3,3, 4};
        const int cols[15] = {0,1,2,3,4, 1,2,3,4, 2,3,4, 3,4, 4};
        float tri[15];
        float sum = 0.f;
#pragma unroll
        for (int i = 0; i < 15; ++i) {
            float r = 0.f;
#pragma unroll
            for (int j = 0; j < 4; ++j) r += Cm[j + rows[i]][j + cols[i]];
            r *= 0.25f;   // mean over J=4 shifts
            tri[i] = r;
            sum += r;
        }
        const float mean = sum * (1.0f / 30.0f);
        float var = 0.f;
#pragma unroll
        for (int i = 0; i < 15; ++i) { const float d = tri[i] - mean; var += d * d; }
        var += 15.0f * mean * mean;   // 15 zero imag entries
        var *= (1.0f / 30.0f);
        const float inv = 1.0f / (sqrtf(var) + EPSV);

        float* o = out + (size_t)n * 30;
#pragma unroll
        for (int i = 0; i < 15; ++i) o[i] = (tri[i] - mean) * inv;
        const float zi = -mean * inv;
#pragma unroll
        for (int i = 0; i < 15; ++i) o[15 + i] = zi;
    }
}

extern "C" void kernel_launch(void* const* d_in, const int* in_sizes, int n_in,
                              void* d_out, int out_size, void* d_ws, size_t ws_size,
                              hipStream_t stream) {
    (void)d_ws; (void)ws_size;   // intentionally unused: avoids ws re-poison fills
    const float* X = (const float*)d_in[0];
    float* out  = (float*)d_out;
    ssf_fused<<<256, NT, 0, stream>>>(X, out);
}